// Round 1
// baseline (2378.496 us; speedup 1.0000x reference)
//
#include <hip/hip_runtime.h>

// StyleBlock: B=8, C=512, H=W=64, K=3.
// Strategy round 1 (fp32 correctness baseline):
//   k1: alpha[b,i]   = c_conv * (c_style * (w[b,:]·SW[i,:]) + sbias[i])
//   k2: wsq[o,i]     = sum_k cw[o,i,k]^2
//   k3: demod[b,o]   = rsqrt( sum_i alpha[b,i]^2 * wsq[o,i] + 1e-8 )
//   k4: direct conv, alpha folded into LDS x-tile, demod folded into epilogue,
//       weights read raw via wave-uniform (scalar) loads.

#define CC 512
#define BB 8
#define HH 64
#define WW 64
#define HWSZ (HH * WW)

#define C_STYLE 0.04419417382415922f   // 1/sqrt(512)
#define C_CONV  0.014731391274719739f  // 1/sqrt(512*9)

// ---------------- k1: style -> alpha ----------------
__global__ void style_alpha_kernel(const float* __restrict__ w,
                                   const float* __restrict__ sw,
                                   const float* __restrict__ sbias,
                                   float* __restrict__ alpha) {
  int t = blockIdx.x * blockDim.x + threadIdx.x;  // [0, B*C)
  int b = t >> 9;
  int j = t & (CC - 1);
  const float* wr = w + b * CC;
  const float* sr = sw + j * CC;
  float acc = 0.f;
  for (int k = 0; k < CC; ++k) acc = fmaf(wr[k], sr[k], acc);
  alpha[t] = C_CONV * fmaf(C_STYLE, acc, sbias[j]);
}

// ---------------- k2: per-(o,i) weight sq-norm ----------------
__global__ void wsq_kernel(const float* __restrict__ cw,
                           float* __restrict__ wsq) {
  int t = blockIdx.x * blockDim.x + threadIdx.x;  // [0, C*C) ; t = o*512+i
  const float* p = cw + (size_t)t * 9;
  float s = 0.f;
#pragma unroll
  for (int k = 0; k < 9; ++k) s = fmaf(p[k], p[k], s);
  wsq[t] = s;
}

// ---------------- k3: demod ----------------
__global__ void demod_kernel(const float* __restrict__ alpha,
                             const float* __restrict__ wsq,
                             float* __restrict__ demod) {
  int t = blockIdx.x * blockDim.x + threadIdx.x;  // [0, B*C) ; t = b*512+o
  int b = t >> 9;
  int o = t & (CC - 1);
  const float* ar = alpha + b * CC;
  const float* qr = wsq + (size_t)o * CC;
  float s = 0.f;
  for (int i = 0; i < CC; ++i) {
    float a = ar[i];
    s = fmaf(a * a, qr[i], s);
  }
  s += 1e-8f;
  float r = rsqrtf(s);
  r = r * fmaf(-0.5f * s * r, r, 1.5f);  // one Newton step for safety
  demod[t] = r;
}

// ---------------- k4: modulated conv + noise + bias + leaky ----------------
// grid: (4 spatial tiles, 32 o-groups, 8 batch); block: 256
// thread: xx = tid&31 (col), yq = tid>>5 (row group of 4), 16 o's, 4 rows.
#define OT 16
__global__ void conv_kernel(const float* __restrict__ x,
                            const float* __restrict__ cw,
                            const float* __restrict__ noise,
                            const float* __restrict__ bias,
                            const float* __restrict__ scale_noise,
                            const float* __restrict__ alpha,
                            const float* __restrict__ demod,
                            float* __restrict__ out) {
  __shared__ float xs[34 * 34];

  const int tile = blockIdx.x;           // 0..3
  const int o0 = blockIdx.y * OT;        // 0..511 step 16
  const int b = blockIdx.z;              // 0..7
  const int tx0 = (tile & 1) * 32;
  const int ty0 = (tile >> 1) * 32;
  const int tid = threadIdx.x;
  const int xx = tid & 31;
  const int yq = tid >> 5;               // 0..7
  const int ybase = yq * 4;

  float acc[OT][4];
#pragma unroll
  for (int oo = 0; oo < OT; ++oo)
#pragma unroll
    for (int p = 0; p < 4; ++p) acc[oo][p] = 0.f;

  const float* xb = x + (size_t)b * CC * HWSZ;
  const float* al = alpha + b * CC;

  for (int i = 0; i < CC; ++i) {
    const float ai = al[i];  // wave-uniform -> scalar load
    const float* xi = xb + (size_t)i * HWSZ;
    __syncthreads();
    // stage 34x34 halo tile, pre-scaled by alpha
    for (int idx = tid; idx < 34 * 34; idx += 256) {
      int r = idx / 34;
      int c = idx - r * 34;
      int gy = ty0 - 1 + r;
      int gx = tx0 - 1 + c;
      float v = 0.f;
      if ((unsigned)gy < 64u && (unsigned)gx < 64u) v = xi[gy * 64 + gx];
      xs[idx] = v * ai;
    }
    __syncthreads();

    // 6x3 register window covering this thread's 4 output rows
    float xv[6][3];
#pragma unroll
    for (int r = 0; r < 6; ++r)
#pragma unroll
      for (int c = 0; c < 3; ++c) xv[r][c] = xs[(ybase + r) * 34 + xx + c];

    const float* wbase = cw + ((size_t)o0 * CC + i) * 9;
#pragma unroll
    for (int oo = 0; oo < OT; ++oo) {
      const float* wp = wbase + (size_t)oo * CC * 9;  // uniform -> s_load
      float w0 = wp[0], w1 = wp[1], w2 = wp[2];
      float w3 = wp[3], w4 = wp[4], w5 = wp[5];
      float w6 = wp[6], w7 = wp[7], w8 = wp[8];
#pragma unroll
      for (int p = 0; p < 4; ++p) {
        float a = acc[oo][p];
        a = fmaf(w0, xv[p + 0][0], a);
        a = fmaf(w1, xv[p + 0][1], a);
        a = fmaf(w2, xv[p + 0][2], a);
        a = fmaf(w3, xv[p + 1][0], a);
        a = fmaf(w4, xv[p + 1][1], a);
        a = fmaf(w5, xv[p + 1][2], a);
        a = fmaf(w6, xv[p + 2][0], a);
        a = fmaf(w7, xv[p + 2][1], a);
        a = fmaf(w8, xv[p + 2][2], a);
        acc[oo][p] = a;
      }
    }
  }

  // epilogue: demod, noise, bias, leaky relu
  const float sn = scale_noise[0];
  const int gx = tx0 + xx;
#pragma unroll
  for (int p = 0; p < 4; ++p) {
    const int gy = ty0 + ybase + p;
    const float nz = sn * noise[b * HWSZ + gy * 64 + gx];
#pragma unroll
    for (int oo = 0; oo < OT; ++oo) {
      const int o = o0 + oo;
      float v = fmaf(acc[oo][p], demod[b * CC + o], nz + bias[o]);
      out[(((size_t)b * CC + o) * HH + gy) * WW + gx] = v > 0.f ? v : 0.2f * v;
    }
  }
}

extern "C" void kernel_launch(void* const* d_in, const int* in_sizes, int n_in,
                              void* d_out, int out_size, void* d_ws, size_t ws_size,
                              hipStream_t stream) {
  const float* x       = (const float*)d_in[0];  // [8,512,64,64]
  const float* w       = (const float*)d_in[1];  // [8,512]
  const float* noise   = (const float*)d_in[2];  // [8,1,64,64]
  const float* cw      = (const float*)d_in[3];  // [512,512,3,3]
  const float* sw      = (const float*)d_in[4];  // [512,512]
  const float* sbias   = (const float*)d_in[5];  // [512]
  const float* bias    = (const float*)d_in[6];  // [512]
  const float* sn      = (const float*)d_in[7];  // [1]
  float* out = (float*)d_out;

  float* alpha = (float*)d_ws;                   // B*C
  float* demod = alpha + BB * CC;                // B*C
  float* wsq   = demod + BB * CC;                // C*C

  style_alpha_kernel<<<dim3((BB * CC) / 256), dim3(256), 0, stream>>>(w, sw, sbias, alpha);
  wsq_kernel<<<dim3((CC * CC) / 256), dim3(256), 0, stream>>>(cw, wsq);
  demod_kernel<<<dim3((BB * CC) / 256), dim3(256), 0, stream>>>(alpha, wsq, demod);
  conv_kernel<<<dim3(4, CC / OT, BB), dim3(256), 0, stream>>>(
      x, cw, noise, bias, sn, alpha, demod, out);
}

// Round 2
// 710.249 us; speedup vs baseline: 3.3488x; 3.3488x over previous
//
#include <hip/hip_runtime.h>

// StyleBlock B=8, C=512, H=W=64, K=3 — bf16 MFMA implicit-GEMM conv.
// y[b,o,p] = demod[b,o] * sum_{i,t} W[o,i,t] * (alpha[b,i]*x[b,i,p+sh(t)])
//            + sn*noise + bias, LeakyReLU(0.2)
// A = weights (pre-packed to MFMA frag order, bf16, global/L2-served)
// B = x*alpha (bf16, LDS tile with halo, [row][col][i] i-padded to 40)
// MFMA 16x16x32 bf16; block = 128 o x 128 px (2 rows), 4 waves 2x2,
// each wave 64x64 via 4x4 frag blocks.

#define CC 512
#define BB 8
#define HWSZ 4096

#define C_STYLE 0.04419417382415922f   // 1/sqrt(512)
#define C_CONV  0.014731391274719739f  // 1/sqrt(512*9)

typedef __attribute__((ext_vector_type(8))) short bf16x8;
typedef __attribute__((ext_vector_type(4))) float f32x4;

static __device__ __forceinline__ short f2bf(float f) {
  unsigned u = __float_as_uint(f);
  unsigned r = (u + 0x7fffu + ((u >> 16) & 1u)) >> 16;  // RNE
  return (short)r;
}

// ---------------- wpack: cw fp32 -> bf16 MFMA-frag order ----------------
// wfrag idx: (((t*16 + ib)*32 + ob)*64 + lane)*8 + j
//   o = ob*16 + (lane&15), i = ib*32 + (lane>>4)*8 + j
__global__ void wpack_kernel(const float* __restrict__ cw,
                             short* __restrict__ wfrag) {
  int t0 = blockIdx.x * blockDim.x + threadIdx.x;  // [0, 512*512)
  int o = t0 >> 9;
  int i = t0 & 511;
  int ib = i >> 5;
  int ob = o >> 4;
  int lane = (o & 15) + (((i >> 3) & 3) << 4);
  int j = i & 7;
  const float* p = cw + (size_t)t0 * 9;
#pragma unroll
  for (int t = 0; t < 9; ++t) {
    wfrag[((((size_t)t * 16 + ib) * 32 + ob) * 64 + lane) * 8 + j] = f2bf(p[t]);
  }
}

// ---------------- style -> alpha (wave per (b,j)) ----------------
__global__ void style_alpha_kernel(const float* __restrict__ w,
                                   const float* __restrict__ sw,
                                   const float* __restrict__ sbias,
                                   float* __restrict__ alpha) {
  int wv = (blockIdx.x * blockDim.x + threadIdx.x) >> 6;  // [0, B*C)
  int lane = threadIdx.x & 63;
  int b = wv >> 9;
  int j = wv & 511;
  float acc = 0.f;
  const float* wr = w + b * CC;
  const float* sr = sw + (size_t)j * CC;
#pragma unroll
  for (int k = 0; k < CC; k += 64) acc = fmaf(wr[k + lane], sr[k + lane], acc);
#pragma unroll
  for (int off = 32; off > 0; off >>= 1) acc += __shfl_down(acc, off);
  if (lane == 0) alpha[wv] = C_CONV * fmaf(C_STYLE, acc, sbias[j]);
}

// ---------------- wsq[o,i] = sum_t cw[o,i,t]^2 ----------------
__global__ void wsq_kernel(const float* __restrict__ cw,
                           float* __restrict__ wsq) {
  int t = blockIdx.x * blockDim.x + threadIdx.x;  // [0, C*C)
  const float* p = cw + (size_t)t * 9;
  float s = 0.f;
#pragma unroll
  for (int k = 0; k < 9; ++k) s = fmaf(p[k], p[k], s);
  wsq[t] = s;
}

// ---------------- demod (wave per (b,o)) ----------------
__global__ void demod_kernel(const float* __restrict__ alpha,
                             const float* __restrict__ wsq,
                             float* __restrict__ demod) {
  int wv = (blockIdx.x * blockDim.x + threadIdx.x) >> 6;  // [0, B*C)
  int lane = threadIdx.x & 63;
  int b = wv >> 9;
  int o = wv & 511;
  const float* ar = alpha + b * CC;
  const float* qr = wsq + (size_t)o * CC;
  float s = 0.f;
#pragma unroll
  for (int i = 0; i < CC; i += 64) {
    float a = ar[i + lane];
    s = fmaf(a * a, qr[i + lane], s);
  }
#pragma unroll
  for (int off = 32; off > 0; off >>= 1) s += __shfl_down(s, off);
  if (lane == 0) {
    s += 1e-8f;
    float r = rsqrtf(s);
    r = r * fmaf(-0.5f * s * r, r, 1.5f);
    demod[wv] = r;
  }
}

// ---------------- conv: MFMA implicit GEMM ----------------
// grid (32 px-groups, 4 o-groups, 8 batch), 256 threads
#define IPAD 40            // 32 i padded to 40 els (80B col stride)
#define LDSN (4 * 66 * IPAD)
__global__ __launch_bounds__(256, 2) void conv_kernel(
    const float* __restrict__ x,
    const short* __restrict__ wfrag,
    const float* __restrict__ noise,
    const float* __restrict__ bias,
    const float* __restrict__ scale_noise,
    const float* __restrict__ alpha,
    const float* __restrict__ demod,
    float* __restrict__ out) {
  __shared__ short xs[LDSN];

  const int b = blockIdx.z;
  const int y0 = blockIdx.x * 2;           // first output row of tile
  const int og = blockIdx.y;               // o-group (128 o's)
  const int tid = threadIdx.x;
  const int lane = tid & 63;
  const int wave = tid >> 6;
  const int wr = wave >> 1;                // wave o-row (0/1)
  const int wc = wave & 1;                 // wave px-row (0/1)
  const int n = lane & 15;
  const int quad = lane >> 4;

  f32x4 acc[4][4];
#pragma unroll
  for (int p = 0; p < 4; ++p)
#pragma unroll
    for (int q = 0; q < 4; ++q) acc[p][q] = (f32x4){0.f, 0.f, 0.f, 0.f};

  const float* xb = x + (size_t)b * CC * HWSZ;
  const float* al = alpha + b * CC;

  for (int ib = 0; ib < 16; ++ib) {
    const int i0 = ib * 32;
    __syncthreads();
    // stage 4 rows x 66 cols x 32 i  (x * alpha, bf16)
#pragma unroll
    for (int it = 0; it < 33; ++it) {
      int idx = tid + it * 256;            // [0, 4*32*66)
      int r = idx / (32 * 66);
      int rem = idx - r * (32 * 66);
      int i = rem / 66;
      int c = rem - i * 66;
      int gy = y0 - 1 + r;
      int gx = c - 1;
      float v = 0.f;
      if ((unsigned)gy < 64u && (unsigned)gx < 64u)
        v = xb[(size_t)(i0 + i) * HWSZ + gy * 64 + gx] * al[i0 + i];
      xs[(r * 66 + c) * IPAD + i] = f2bf(v);
    }
    __syncthreads();

#pragma unroll
    for (int t = 0; t < 9; ++t) {
      const int dy = t / 3 - 1;
      const int dx = t % 3 - 1;
      // A frags: global, pre-packed frag order
      const short* wp = wfrag +
          ((((size_t)t * 16 + ib) * 32 + (og * 8 + wr * 4)) * 64) * 8;
      bf16x8 af[4];
#pragma unroll
      for (int p = 0; p < 4; ++p)
        af[p] = *(const bf16x8*)(wp + ((size_t)p * 64 + lane) * 8);
      // B frags: LDS, row = wc+dy+1, col = 1 + q*16 + n + dx
      const int rowb = (wc + dy + 1) * 66 + 1 + n + dx;
      bf16x8 bf[4];
#pragma unroll
      for (int q = 0; q < 4; ++q)
        bf[q] = *(const bf16x8*)(xs + (rowb + q * 16) * IPAD + quad * 8);
#pragma unroll
      for (int p = 0; p < 4; ++p)
#pragma unroll
        for (int q = 0; q < 4; ++q)
          acc[p][q] = __builtin_amdgcn_mfma_f32_16x16x32_bf16(
              af[p], bf[q], acc[p][q], 0, 0, 0);
    }
  }

  // epilogue: demod, noise, bias, leaky
  const float sn = scale_noise[0];
  const int y = y0 + wc;
  const int obase = og * 128 + wr * 64;
#pragma unroll
  for (int q = 0; q < 4; ++q) {
    const int col = q * 16 + n;
    const float nz = sn * noise[b * HWSZ + y * 64 + col];
#pragma unroll
    for (int p = 0; p < 4; ++p) {
      const int o0 = obase + p * 16 + quad * 4;
#pragma unroll
      for (int r = 0; r < 4; ++r) {
        const int o = o0 + r;
        float v = fmaf(acc[p][q][r], demod[b * CC + o], nz + bias[o]);
        out[((size_t)(b * CC + o)) * HWSZ + y * 64 + col] =
            v > 0.f ? v : 0.2f * v;
      }
    }
  }
}

extern "C" void kernel_launch(void* const* d_in, const int* in_sizes, int n_in,
                              void* d_out, int out_size, void* d_ws, size_t ws_size,
                              hipStream_t stream) {
  const float* x     = (const float*)d_in[0];
  const float* w     = (const float*)d_in[1];
  const float* noise = (const float*)d_in[2];
  const float* cw    = (const float*)d_in[3];
  const float* sw    = (const float*)d_in[4];
  const float* sbias = (const float*)d_in[5];
  const float* bias  = (const float*)d_in[6];
  const float* sn    = (const float*)d_in[7];
  float* out = (float*)d_out;

  float* alpha = (float*)d_ws;                        // B*C
  float* demod = alpha + BB * CC;                     // B*C
  float* wsq   = demod + BB * CC;                     // C*C
  short* wfrag = (short*)(wsq + CC * CC);             // 9*16*32*64*8 bf16

  wpack_kernel<<<dim3((CC * CC) / 256), 256, 0, stream>>>(cw, wfrag);
  style_alpha_kernel<<<dim3(BB * CC / 4), 256, 0, stream>>>(w, sw, sbias, alpha);
  wsq_kernel<<<dim3((CC * CC) / 256), 256, 0, stream>>>(cw, wsq);
  demod_kernel<<<dim3(BB * CC / 4), 256, 0, stream>>>(alpha, wsq, demod);
  conv_kernel<<<dim3(32, 4, BB), 256, 0, stream>>>(
      x, wfrag, noise, bias, sn, alpha, demod, out);
}

// Round 4
// 340.573 us; speedup vs baseline: 6.9838x; 2.0855x over previous
//
#include <hip/hip_runtime.h>

// StyleBlock B=8, C=512, H=W=64, K=3 — bf16 MFMA implicit-GEMM conv, round 4.
// Round-3 structure with the B-fragment LDS address bug fixed
// (q*16 chunks, not q*16*66).
// Pipeline:
//   style_alpha: alpha[b,i] = c_conv*(c_style*(w·SW^T) + sbias)
//   wpack:       cw fp32 -> bf16 A-fragments (MFMA lane order)
//   wsq/demod:   demod[b,o] = rsqrt(sum_i alpha^2 * ||cw[o,i,:]||^2 + eps)
//   xborder/xprep: xT[b][ic][py 66][px 66][8i] bf16 = alpha*x, zero halo
//   conv:        implicit GEMM, B staged via global_load_lds(16B), A from L2.

#define CC 512
#define BB 8
#define HWSZ 4096

#define C_STYLE 0.04419417382415922f   // 1/sqrt(512)
#define C_CONV  0.014731391274719739f  // 1/sqrt(512*9)

typedef __attribute__((ext_vector_type(8))) short bf16x8;
typedef __attribute__((ext_vector_type(4))) float f32x4;

static __device__ __forceinline__ short f2bf(float f) {
  unsigned u = __float_as_uint(f);
  unsigned r = (u + 0x7fffu + ((u >> 16) & 1u)) >> 16;  // RNE
  return (short)r;
}

static __device__ __forceinline__ void load_lds_16(const void* g, void* l) {
  __builtin_amdgcn_global_load_lds(
      (const __attribute__((address_space(1))) unsigned int*)g,
      (__attribute__((address_space(3))) unsigned int*)l, 16, 0, 0);
}

// ---------------- wpack: cw fp32 -> bf16 MFMA-frag order ----------------
// wfrag idx: (((t*16 + ib32)*32 + ob)*64 + lane)*8 + j
//   o = ob*16 + (lane&15), i = ib32*32 + ((lane>>4)&3)*8 + j
__global__ void wpack_kernel(const float* __restrict__ cw,
                             short* __restrict__ wfrag) {
  int t0 = blockIdx.x * blockDim.x + threadIdx.x;  // [0, 512*512)
  int o = t0 >> 9;
  int i = t0 & 511;
  int ib32 = i >> 5;
  int ob = o >> 4;
  int lane = (o & 15) + (((i >> 3) & 3) << 4);
  int j = i & 7;
  const float* p = cw + (size_t)t0 * 9;
#pragma unroll
  for (int t = 0; t < 9; ++t) {
    wfrag[((((size_t)t * 16 + ib32) * 32 + ob) * 64 + lane) * 8 + j] = f2bf(p[t]);
  }
}

// ---------------- style -> alpha (wave per (b,j)) ----------------
__global__ void style_alpha_kernel(const float* __restrict__ w,
                                   const float* __restrict__ sw,
                                   const float* __restrict__ sbias,
                                   float* __restrict__ alpha) {
  int wv = (blockIdx.x * blockDim.x + threadIdx.x) >> 6;  // [0, B*C)
  int lane = threadIdx.x & 63;
  int b = wv >> 9;
  int j = wv & 511;
  float acc = 0.f;
  const float* wr = w + b * CC;
  const float* sr = sw + (size_t)j * CC;
#pragma unroll
  for (int k = 0; k < CC; k += 64) acc = fmaf(wr[k + lane], sr[k + lane], acc);
#pragma unroll
  for (int off = 32; off > 0; off >>= 1) acc += __shfl_down(acc, off);
  if (lane == 0) alpha[wv] = C_CONV * fmaf(C_STYLE, acc, sbias[j]);
}

// ---------------- wsq[o,i] = sum_t cw[o,i,t]^2 ----------------
__global__ void wsq_kernel(const float* __restrict__ cw,
                           float* __restrict__ wsq) {
  int t = blockIdx.x * blockDim.x + threadIdx.x;  // [0, C*C)
  const float* p = cw + (size_t)t * 9;
  float s = 0.f;
#pragma unroll
  for (int k = 0; k < 9; ++k) s = fmaf(p[k], p[k], s);
  wsq[t] = s;
}

// ---------------- demod (wave per (b,o)) ----------------
__global__ void demod_kernel(const float* __restrict__ alpha,
                             const float* __restrict__ wsq,
                             float* __restrict__ demod) {
  int wv = (blockIdx.x * blockDim.x + threadIdx.x) >> 6;  // [0, B*C)
  int lane = threadIdx.x & 63;
  int b = wv >> 9;
  int o = wv & 511;
  const float* ar = alpha + b * CC;
  const float* qr = wsq + (size_t)o * CC;
  float s = 0.f;
#pragma unroll
  for (int i = 0; i < CC; i += 64) {
    float a = ar[i + lane];
    s = fmaf(a * a, qr[i + lane], s);
  }
#pragma unroll
  for (int off = 32; off > 0; off >>= 1) s += __shfl_down(s, off);
  if (lane == 0) {
    s += 1e-8f;
    float r = rsqrtf(s);
    r = r * fmaf(-0.5f * s * r, r, 1.5f);
    demod[wv] = r;
  }
}

// ---------------- xT border zero: 260 border cells per (b,ic) ----------------
__global__ void xborder_kernel(short* __restrict__ xT) {
  int t = blockIdx.x * blockDim.x + threadIdx.x;  // [0, 8*64*260)
  if (t >= BB * 64 * 260) return;
  int b = t / (64 * 260);
  int r = t - b * (64 * 260);
  int ic = r / 260;
  int cell = r - ic * 260;
  int py, px;
  if (cell < 66)       { py = 0;  px = cell; }
  else if (cell < 132) { py = 65; px = cell - 66; }
  else if (cell < 196) { py = cell - 132 + 1; px = 0; }
  else                 { py = cell - 196 + 1; px = 65; }
  bf16x8 z = (bf16x8){0, 0, 0, 0, 0, 0, 0, 0};
  *(bf16x8*)(xT + ((((size_t)b * 64 + ic) * 66 + py) * 66 + px) * 8) = z;
}

// ---------------- xprep: xT interior = bf16(alpha * x), i8-interleaved ------
// grid (64 gy, 16 icg, 8 b), block 256: icq = tid>>6, px = tid&63
__global__ void xprep_kernel(const float* __restrict__ x,
                             const float* __restrict__ alpha,
                             short* __restrict__ xT) {
  const int gy = blockIdx.x;
  const int ic = blockIdx.y * 4 + (threadIdx.x >> 6);
  const int b = blockIdx.z;
  const int px = threadIdx.x & 63;
  const float* xp = x + (((size_t)b * CC + ic * 8) * HWSZ + gy * 64 + px);
  const float* al = alpha + b * CC + ic * 8;
  bf16x8 v;
#pragma unroll
  for (int j = 0; j < 8; ++j) v[j] = f2bf(xp[(size_t)j * HWSZ] * al[j]);
  *(bf16x8*)(xT + ((((size_t)b * 64 + ic) * 66 + gy + 1) * 66 + px + 1) * 8) = v;
}

// ---------------- conv: MFMA implicit GEMM ----------------
// grid 1024 blocks (swizzled: b = lin&7), 256 threads = 4 waves (wr x wc).
// Block tile: 128 o x (2 rows x 64 px). K-loop: 8 ibs of 64 i.
// LDS: chunks [kc 8][r 4][c 66] x 16B = 33792 B (2112 chunks).
#define NCHUNK 2112
__global__ __launch_bounds__(256, 4) void conv_kernel(
    const short* __restrict__ xT,
    const short* __restrict__ wfrag,
    const float* __restrict__ noise,
    const float* __restrict__ bias,
    const float* __restrict__ scale_noise,
    const float* __restrict__ demod,
    float* __restrict__ out) {
  __shared__ __align__(16) short xs[NCHUNK * 8];

  const int lin = blockIdx.x + 32 * blockIdx.y + 128 * blockIdx.z;
  const int b = lin & 7;                    // XCD-locality swizzle
  const int r2 = lin >> 3;
  const int og = r2 & 3;                    // 128-o group
  const int y0 = (r2 >> 2) * 2;             // first output row
  const int tid = threadIdx.x;
  const int lane = tid & 63;
  const int wave = tid >> 6;
  const int wr = wave >> 1;                 // o half (0/1)
  const int wc = wave & 1;                  // px row (0/1)
  const int n = lane & 15;
  const int quad = lane >> 4;

  f32x4 acc[4][4];
#pragma unroll
  for (int p = 0; p < 4; ++p)
#pragma unroll
    for (int q = 0; q < 4; ++q) acc[p][q] = (f32x4){0.f, 0.f, 0.f, 0.f};

  // staging descriptors: chunk cid = (kc*4 + r)*66 + c  ->  global chunk
  // g = ((b*64 + ib*8 + kc)*66 + (y0+r))*66 + c ; per-ib advance 8*66*66 chunks
  const char* xTb = (const char*)xT;
  unsigned goff[9];
#pragma unroll
  for (int it = 0; it < 9; ++it) {
    int cid = tid + it * 256;
    int kc = cid / 264;
    int rem = cid - kc * 264;
    int r = rem / 66;
    int c = rem - r * 66;
    goff[it] = (unsigned)((((b * 64 + kc) * 66 + (y0 + r)) * 66 + c) * 16);
  }

  const short* wf0 = wfrag + ((size_t)(og * 8 + wr * 4) * 64 + lane) * 8;

  for (int ib = 0; ib < 8; ++ib) {
    __syncthreads();
#pragma unroll
    for (int it = 0; it < 9; ++it) {
      int cid = tid + it * 256;
      if (cid < NCHUNK)
        load_lds_16(xTb + goff[it], xs + (size_t)cid * 8);
      goff[it] += 8 * 66 * 66 * 16;
    }
    __syncthreads();

#pragma unroll
    for (int kstep = 0; kstep < 2; ++kstep) {
      const int ib32 = ib * 2 + kstep;
#pragma unroll
      for (int t = 0; t < 9; ++t) {
        const int dy = t / 3 - 1;
        const int dx = t % 3 - 1;
        const short* wp = wf0 + (size_t)(t * 16 + ib32) * 16384;
        bf16x8 af[4];
#pragma unroll
        for (int p = 0; p < 4; ++p)
          af[p] = *(const bf16x8*)(wp + p * 512);
        const int row = wc + dy + 1;
        const short* bp =
            xs + (((kstep * 4 + quad) * 4 + row) * 66 + 1 + n + dx) * 8;
        bf16x8 bf[4];
#pragma unroll
        for (int q = 0; q < 4; ++q)
          bf[q] = *(const bf16x8*)(bp + q * 16 * 8);  // +q*16 chunks (FIXED)
#pragma unroll
        for (int p = 0; p < 4; ++p)
#pragma unroll
          for (int q = 0; q < 4; ++q)
            acc[p][q] = __builtin_amdgcn_mfma_f32_16x16x32_bf16(
                af[p], bf[q], acc[p][q], 0, 0, 0);
      }
    }
  }

  // epilogue: demod, noise, bias, leaky
  const float sn = scale_noise[0];
  const int y = y0 + wc;
  const int obase = og * 128 + wr * 64;
#pragma unroll
  for (int q = 0; q < 4; ++q) {
    const int col = q * 16 + n;
    const float nz = sn * noise[b * HWSZ + y * 64 + col];
#pragma unroll
    for (int p = 0; p < 4; ++p) {
      const int o0 = obase + p * 16 + quad * 4;
#pragma unroll
      for (int r = 0; r < 4; ++r) {
        const int o = o0 + r;
        float v = fmaf(acc[p][q][r], demod[b * CC + o], nz + bias[o]);
        out[((size_t)(b * CC + o)) * HWSZ + y * 64 + col] =
            v > 0.f ? v : 0.2f * v;
      }
    }
  }
}

extern "C" void kernel_launch(void* const* d_in, const int* in_sizes, int n_in,
                              void* d_out, int out_size, void* d_ws, size_t ws_size,
                              hipStream_t stream) {
  const float* x     = (const float*)d_in[0];
  const float* w     = (const float*)d_in[1];
  const float* noise = (const float*)d_in[2];
  const float* cw    = (const float*)d_in[3];
  const float* sw    = (const float*)d_in[4];
  const float* sbias = (const float*)d_in[5];
  const float* bias  = (const float*)d_in[6];
  const float* sn    = (const float*)d_in[7];
  float* out = (float*)d_out;

  float* alpha = (float*)d_ws;                        // 4096 f
  float* demod = alpha + BB * CC;                     // 4096 f
  float* wsq   = demod + BB * CC;                     // 262144 f
  short* wfrag = (short*)(wsq + CC * CC);             // 9*16*32*64*8 = 2359296 bf16
  short* xT    = wfrag + (size_t)9 * 16 * 32 * 64 * 8;  // 8*64*66*66*8 bf16

  style_alpha_kernel<<<dim3(BB * CC / 4), 256, 0, stream>>>(w, sw, sbias, alpha);
  wpack_kernel<<<dim3((CC * CC) / 256), 256, 0, stream>>>(cw, wfrag);
  wsq_kernel<<<dim3((CC * CC) / 256), 256, 0, stream>>>(cw, wsq);
  demod_kernel<<<dim3(BB * CC / 4), 256, 0, stream>>>(alpha, wsq, demod);
  xborder_kernel<<<dim3((BB * 64 * 260 + 255) / 256), 256, 0, stream>>>(xT);
  xprep_kernel<<<dim3(64, 16, BB), 256, 0, stream>>>(x, alpha, xT);
  conv_kernel<<<dim3(32, 4, BB), 256, 0, stream>>>(
      xT, wfrag, noise, bias, sn, demod, out);
}

// Round 5
// 306.413 us; speedup vs baseline: 7.7624x; 1.1115x over previous
//
#include <hip/hip_runtime.h>

// StyleBlock B=8, C=512, H=W=64, K=3 — bf16 MFMA implicit-GEMM conv, round 5.
// vs round 4: block tile 256o x 128px (2 blocks/CU, 256 regs/wave -> room to
// software-pipeline A/B frag loads), LDS reads per MFMA halved; prep fused
// (wpack+wsq, border folded into xprep): 5 launches.

#define CC 512
#define BB 8
#define HWSZ 4096

#define C_STYLE 0.04419417382415922f   // 1/sqrt(512)
#define C_CONV  0.014731391274719739f  // 1/sqrt(512*9)

typedef __attribute__((ext_vector_type(8))) short bf16x8;
typedef __attribute__((ext_vector_type(4))) float f32x4;

static __device__ __forceinline__ short f2bf(float f) {
  unsigned u = __float_as_uint(f);
  unsigned r = (u + 0x7fffu + ((u >> 16) & 1u)) >> 16;  // RNE
  return (short)r;
}

static __device__ __forceinline__ void load_lds_16(const void* g, void* l) {
  __builtin_amdgcn_global_load_lds(
      (const __attribute__((address_space(1))) unsigned int*)g,
      (__attribute__((address_space(3))) unsigned int*)l, 16, 0, 0);
}

// ------------- wprep: cw fp32 -> bf16 A-frags + wsq (fused) -------------
// wfrag idx: (((t*16 + ib32)*32 + ob)*64 + lane)*8 + j
//   o = ob*16 + (lane&15), i = ib32*32 + ((lane>>4)&3)*8 + j
__global__ void wprep_kernel(const float* __restrict__ cw,
                             short* __restrict__ wfrag,
                             float* __restrict__ wsq) {
  int t0 = blockIdx.x * blockDim.x + threadIdx.x;  // [0, 512*512) = o*512+i
  int o = t0 >> 9;
  int i = t0 & 511;
  int ib32 = i >> 5;
  int ob = o >> 4;
  int lane = (o & 15) + (((i >> 3) & 3) << 4);
  int j = i & 7;
  const float* p = cw + (size_t)t0 * 9;
  float s = 0.f;
#pragma unroll
  for (int t = 0; t < 9; ++t) {
    float v = p[t];
    s = fmaf(v, v, s);
    wfrag[((((size_t)t * 16 + ib32) * 32 + ob) * 64 + lane) * 8 + j] = f2bf(v);
  }
  wsq[t0] = s;
}

// ---------------- style -> alpha (wave per (b,j)) ----------------
__global__ void style_alpha_kernel(const float* __restrict__ w,
                                   const float* __restrict__ sw,
                                   const float* __restrict__ sbias,
                                   float* __restrict__ alpha) {
  int wv = (blockIdx.x * blockDim.x + threadIdx.x) >> 6;  // [0, B*C)
  int lane = threadIdx.x & 63;
  int b = wv >> 9;
  int j = wv & 511;
  float acc = 0.f;
  const float* wr = w + b * CC;
  const float* sr = sw + (size_t)j * CC;
#pragma unroll
  for (int k = 0; k < CC; k += 64) acc = fmaf(wr[k + lane], sr[k + lane], acc);
#pragma unroll
  for (int off = 32; off > 0; off >>= 1) acc += __shfl_down(acc, off);
  if (lane == 0) alpha[wv] = C_CONV * fmaf(C_STYLE, acc, sbias[j]);
}

// ---------------- demod (wave per (b,o)) ----------------
__global__ void demod_kernel(const float* __restrict__ alpha,
                             const float* __restrict__ wsq,
                             float* __restrict__ demod) {
  int wv = (blockIdx.x * blockDim.x + threadIdx.x) >> 6;  // [0, B*C)
  int lane = threadIdx.x & 63;
  int b = wv >> 9;
  int o = wv & 511;
  const float* ar = alpha + b * CC;
  const float* qr = wsq + (size_t)o * CC;
  float s = 0.f;
#pragma unroll
  for (int i = 0; i < CC; i += 64) {
    float a = ar[i + lane];
    s = fmaf(a * a, qr[i + lane], s);
  }
#pragma unroll
  for (int off = 32; off > 0; off >>= 1) s += __shfl_down(s, off);
  if (lane == 0) {
    s += 1e-8f;
    float r = rsqrtf(s);
    r = r * fmaf(-0.5f * s * r, r, 1.5f);
    demod[wv] = r;
  }
}

// ------- xprep: xT[b][ic][py 66][px 66][8i] = bf16(alpha*x), halo zero -----
// grid (66 py, 16 icg, 8 b), block 256: icq = tid>>6, px = tid&63
__global__ void xprep_kernel(const float* __restrict__ x,
                             const float* __restrict__ alpha,
                             short* __restrict__ xT) {
  const int py = blockIdx.x;               // 0..65
  const int ic = blockIdx.y * 4 + (threadIdx.x >> 6);
  const int b = blockIdx.z;
  const int px = threadIdx.x & 63;
  bf16x8 v = (bf16x8){0, 0, 0, 0, 0, 0, 0, 0};
  if (py >= 1 && py <= 64) {
    const float* xp = x + (((size_t)b * CC + ic * 8) * HWSZ + (py - 1) * 64 + px);
    const float* al = alpha + b * CC + ic * 8;
#pragma unroll
    for (int j = 0; j < 8; ++j) v[j] = f2bf(xp[(size_t)j * HWSZ] * al[j]);
  }
  short* row = xT + (((size_t)(b * 64 + ic) * 66 + py) * 66) * 8;
  *(bf16x8*)(row + (px + 1) * 8) = v;
  bf16x8 z = (bf16x8){0, 0, 0, 0, 0, 0, 0, 0};
  if (px == 0) *(bf16x8*)(row) = z;
  if (px == 63) *(bf16x8*)(row + 65 * 8) = z;
}

// ---------------- conv: MFMA implicit GEMM ----------------
// grid 512 blocks (swizzled: b = lin&7), 256 threads = 4 waves (wr x wc).
// Block tile: 256 o x (2 rows x 64 px). K-loop: 8 ibs of 64 i.
// LDS: chunks [kc 8][r 4][c 66] x 16B = 33792 B (2112 chunks).
#define NCHUNK 2112
__global__ __launch_bounds__(256, 2) void conv_kernel(
    const short* __restrict__ xT,
    const short* __restrict__ wfrag,
    const float* __restrict__ noise,
    const float* __restrict__ bias,
    const float* __restrict__ scale_noise,
    const float* __restrict__ demod,
    float* __restrict__ out) {
  __shared__ __align__(16) short xs[NCHUNK * 8];

  const int lin = blockIdx.x + 32 * blockIdx.y + 64 * blockIdx.z;
  const int b = lin & 7;                    // XCD-locality swizzle
  const int r2 = lin >> 3;
  const int G = r2 & 1;                     // 256-o group
  const int y0 = (r2 >> 1) * 2;             // first output row
  const int tid = threadIdx.x;
  const int lane = tid & 63;
  const int wave = tid >> 6;
  const int wr = wave >> 1;                 // o half within each og2 (0/1)
  const int wc = wave & 1;                  // px row (0/1)
  const int n = lane & 15;
  const int quad = lane >> 4;

  f32x4 acc[2][4][4];                       // [og2][p][q]
#pragma unroll
  for (int g = 0; g < 2; ++g)
#pragma unroll
    for (int p = 0; p < 4; ++p)
#pragma unroll
      for (int q = 0; q < 4; ++q) acc[g][p][q] = (f32x4){0.f, 0.f, 0.f, 0.f};

  // staging descriptors: chunk cid = (kc*4 + r)*66 + c  ->  global chunk
  // g = ((b*64 + ib*8 + kc)*66 + (y0+r))*66 + c ; per-ib advance 8*66*66 chunks
  const char* xTb = (const char*)xT;
  unsigned goff[9];
#pragma unroll
  for (int it = 0; it < 9; ++it) {
    int cid = tid + it * 256;
    int kc = cid / 264;
    int rem = cid - kc * 264;
    int r = rem / 66;
    int c = rem - r * 66;
    goff[it] = (unsigned)((((b * 64 + kc) * 66 + (y0 + r)) * 66 + c) * 16);
  }

  // A bases for the two 128-o halves of this 256-o group
  const short* wf0 = wfrag + ((size_t)((G * 16) + wr * 4) * 64 + lane) * 8;
  // second og2 half is +8 ob = +4096 shorts within each (t,ib32) slab

  for (int ib = 0; ib < 8; ++ib) {
    __syncthreads();
#pragma unroll
    for (int it = 0; it < 9; ++it) {
      int cid = tid + it * 256;
      if (cid < NCHUNK)
        load_lds_16(xTb + goff[it], xs + (size_t)cid * 8);
      goff[it] += 8 * 66 * 66 * 16;
    }
    __syncthreads();

#pragma unroll
    for (int kstep = 0; kstep < 2; ++kstep) {
      const int ib32 = ib * 2 + kstep;
#pragma unroll
      for (int t = 0; t < 9; ++t) {
        const int dy = t / 3 - 1;
        const int dx = t % 3 - 1;
        const short* wp = wf0 + (size_t)(t * 16 + ib32) * 16384;
        bf16x8 af[2][4];
#pragma unroll
        for (int p = 0; p < 4; ++p) {
          af[0][p] = *(const bf16x8*)(wp + p * 512);
          af[1][p] = *(const bf16x8*)(wp + p * 512 + 4096);
        }
        const int row = wc + dy + 1;
        const short* bp =
            xs + (((kstep * 4 + quad) * 4 + row) * 66 + 1 + n + dx) * 8;
        bf16x8 bf[4];
#pragma unroll
        for (int q = 0; q < 4; ++q)
          bf[q] = *(const bf16x8*)(bp + q * 16 * 8);
#pragma unroll
        for (int g = 0; g < 2; ++g)
#pragma unroll
          for (int p = 0; p < 4; ++p)
#pragma unroll
            for (int q = 0; q < 4; ++q)
              acc[g][p][q] = __builtin_amdgcn_mfma_f32_16x16x32_bf16(
                  af[g][p], bf[q], acc[g][p][q], 0, 0, 0);
      }
    }
  }

  // epilogue: demod, noise, bias, leaky
  const float sn = scale_noise[0];
  const int y = y0 + wc;
#pragma unroll
  for (int q = 0; q < 4; ++q) {
    const int col = q * 16 + n;
    const float nz = sn * noise[b * HWSZ + y * 64 + col];
#pragma unroll
    for (int g = 0; g < 2; ++g) {
      const int obase = (G * 2 + g) * 128 + wr * 64;
#pragma unroll
      for (int p = 0; p < 4; ++p) {
        const int o0 = obase + p * 16 + quad * 4;
#pragma unroll
        for (int r = 0; r < 4; ++r) {
          const int o = o0 + r;
          float v = fmaf(acc[g][p][q][r], demod[b * CC + o], nz + bias[o]);
          out[((size_t)(b * CC + o)) * HWSZ + y * 64 + col] =
              v > 0.f ? v : 0.2f * v;
        }
      }
    }
  }
}

extern "C" void kernel_launch(void* const* d_in, const int* in_sizes, int n_in,
                              void* d_out, int out_size, void* d_ws, size_t ws_size,
                              hipStream_t stream) {
  const float* x     = (const float*)d_in[0];
  const float* w     = (const float*)d_in[1];
  const float* noise = (const float*)d_in[2];
  const float* cw    = (const float*)d_in[3];
  const float* sw    = (const float*)d_in[4];
  const float* sbias = (const float*)d_in[5];
  const float* bias  = (const float*)d_in[6];
  const float* sn    = (const float*)d_in[7];
  float* out = (float*)d_out;

  float* alpha = (float*)d_ws;                        // 4096 f
  float* demod = alpha + BB * CC;                     // 4096 f
  float* wsq   = demod + BB * CC;                     // 262144 f
  short* wfrag = (short*)(wsq + CC * CC);             // 9*16*32*64*8 = 2359296 bf16
  short* xT    = wfrag + (size_t)9 * 16 * 32 * 64 * 8;  // 8*64*66*66*8 bf16

  style_alpha_kernel<<<dim3(BB * CC / 4), 256, 0, stream>>>(w, sw, sbias, alpha);
  wprep_kernel<<<dim3((CC * CC) / 256), 256, 0, stream>>>(cw, wfrag, wsq);
  demod_kernel<<<dim3(BB * CC / 4), 256, 0, stream>>>(alpha, wsq, demod);
  xprep_kernel<<<dim3(66, 16, BB), 256, 0, stream>>>(x, alpha, xT);
  conv_kernel<<<dim3(32, 2, BB), 256, 0, stream>>>(
      xT, wfrag, noise, bias, sn, demod, out);
}